// Round 2
// baseline (568.393 us; speedup 1.0000x reference)
//
#include <hip/hip_runtime.h>

#define BB 4
#define S 128
#define SS (S*S)
#define BSS (BB*SS)

// ws plane indices (each plane = BSS floats = 256 KB; total 27 planes = 6.75 MB)
#define WQ_B  0
#define WQ_E  1
#define WQ_S  2
#define WQ_BT 3
#define WQ_ET 4
#define WQ_ST 5
#define WP0   6   // merged be+bb+cb partial (plane 0)
#define WP1   7   // merged eb+ee+ce partial (plane 1)
#define WP2   8   // sp partial (plane 2)
#define WAE0  9   // gb edge-grd partial (plane 0)
#define WAE1  10  // ge edge-grd partial (plane 1)
#define WRS7  11  // ..18: gb span partials per Is (plane 2)
#define WRS8  19  // ..26: ge span partials per Is (plane 2)

__device__ __forceinline__ int off3(int b, int i, int j) { return (b * S + i) * S + j; }
__device__ __forceinline__ int off4(int b, int i, int j, int k) { return ((b * S + i) * S + j) * S + k; }

// ---------------------------------------------------------------------------
// combine + sigmoid + LDS-tiled transpose.
// mode 0: base = src, q = sigmoid(src)          (iteration 0 init)
// mode 1: base += sum(partials), q = sigmoid    (iterations 1,2)
// mode 2: base += sum(partials) only            (final output)
// All partial planes are single-writer plain stores from k_terms (no atomics).
// ---------------------------------------------------------------------------
__global__ __launch_bounds__(256) void k_sigmoid(const float* __restrict__ sb,
                                                 const float* __restrict__ se,
                                                 const float* __restrict__ ss,
                                                 float* __restrict__ base,
                                                 float* __restrict__ ws, int mode) {
    const int b = blockIdx.z, p = blockIdx.y;
    const int ti = blockIdx.x >> 2, tj = blockIdx.x & 3;
    const int col = threadIdx.x & 31, r0 = threadIdx.x >> 5;
    __shared__ float tile[32][33];
    float* bp = base + p * BSS;

#pragma unroll
    for (int rr = 0; rr < 4; ++rr) {
        const int row = r0 + 8 * rr;
        const int gi = 32 * ti + row, gj = 32 * tj + col;
        const int idx = off3(b, gi, gj);
        float v;
        if (mode == 0) {
            const float* src = (p == 0) ? sb : (p == 1) ? se : ss;
            v = src[idx];
        } else {
            v = bp[idx];
            if (p == 0) {
                v += ws[WP0 * BSS + idx] + ws[WAE0 * BSS + idx];
            } else if (p == 1) {
                v += ws[WP1 * BSS + idx] + ws[WAE1 * BSS + idx];
            } else {
                v += ws[WP2 * BSS + idx];
#pragma unroll
                for (int n = 0; n < 16; ++n) v += ws[(WRS7 + n) * BSS + idx];
            }
        }
        bp[idx] = v;
        if (mode < 2) {
            const float q = 1.0f / (1.0f + __expf(-v));
            ws[p * BSS + idx] = q;
            tile[row][col] = q;
        }
    }
    if (mode == 2) return;
    __syncthreads();
#pragma unroll
    for (int rr = 0; rr < 4; ++rr) {
        const int rowo = r0 + 8 * rr;
        ws[(3 + p) * BSS + off3(b, 32 * tj + rowo, 32 * ti + col)] = tile[col][rowo];
    }
}

// ---------------------------------------------------------------------------
// ZERO-ATOMIC term kernel. grid = (128, 5, B).
// yy=0: be+bb+cb -> P0 row I (plain float4 row store via LDS pack)
// yy=1: eb+ee+ce -> P1 row I
// yy=2: sp       -> P2 row I
// yy=3: gb       -> accE plane WAE0 (single-writer) + rs float4 -> WRS7+Is
// yy=4: ge       -> accE plane WAE1 + rs scalar    -> WRS8+Is
// ---------------------------------------------------------------------------
__global__ __launch_bounds__(256) void k_terms(
    const float* __restrict__ be, const float* __restrict__ bb,
    const float* __restrict__ cb, const float* __restrict__ eb,
    const float* __restrict__ ee, const float* __restrict__ ce,
    const float* __restrict__ sp, const float* __restrict__ gb,
    const float* __restrict__ ge, const int* __restrict__ edge,
    const int* __restrict__ chart, float* __restrict__ ws) {
    const int b = blockIdx.z, yy = blockIdx.y, x = blockIdx.x;
    const int t = threadIdx.x, hw = t >> 5, lh = t & 31, l = t & 63;
    const int K = 4 * lh;
    __shared__ float rowbuf[128];

    const float* qb = ws;
    const float* qe = ws + BSS;
    const float* qs = ws + 2 * BSS;
    const float* qbT = ws + 3 * BSS;
    const float* qeT = ws + 4 * BSS;
    const float* qsT = ws + 5 * BSS;

    if (yy < 3) {
        const int I = x;
        unsigned long long Mlo, Mhi;
        if (yy == 2) {
            const int Iprev = (I + S - 1) & (S - 1);
            Mlo = __ballot(chart[off3(b, 0, l)] != 0) & __ballot(chart[off3(b, Iprev, l)] != 0);
            Mhi = __ballot(chart[off3(b, 0, 64 + l)] != 0) & __ballot(chart[off3(b, Iprev, 64 + l)] != 0);
        } else {
            Mlo = __ballot(edge[off3(b, I, l)] != 0);
            Mhi = __ballot(edge[off3(b, I, 64 + l)] != 0);
        }
        const int4 ekv = *(const int4*)&edge[off3(b, I, K)];
        float acc[16];

        if (yy == 2) {
            const int4 c0kv = *(const int4*)&chart[off3(b, 0, K)];
            const float4 qv = *(const float4*)&qs[off3(b, I, K)];
            float pm[4];
#pragma unroll
            for (int c = 0; c < 4; ++c) pm[c] = ((&c0kv.x)[c] != 0) ? (&qv.x)[c] : 0.f;
#pragma unroll
            for (int jj = 0; jj < 16; ++jj) {
                const int j = 8 * jj + hw;
                const float4 v = *(const float4*)&sp[off4(b, I, j, K)];
                float d = pm[0] * v.x + pm[1] * v.y + pm[2] * v.z + pm[3] * v.w;
                const int ci = I > j ? I : j;
#pragma unroll
                for (int c = 0; c < 4; ++c) d -= (K + c == ci) ? pm[c] * (&v.x)[c] : 0.f;
                acc[jj] = d;
            }
        } else {
            const float4 qbv = *(const float4*)&qb[off3(b, I, K)];
            const float4 qev = *(const float4*)&qe[off3(b, I, K)];
            float pmA[4], pmB[4];
            bool pmk[4];
#pragma unroll
            for (int c = 0; c < 4; ++c) {
                const bool ek = (&ekv.x)[c] != 0;
                const bool nI = (I != K + c);
                pmk[c] = ek && nI;
                if (yy == 0) { pmA[c] = pmk[c] ? (&qev.x)[c] : 0.f; pmB[c] = pmk[c] ? (&qbv.x)[c] : 0.f; }
                else         { pmA[c] = ek     ? (&qbv.x)[c] : 0.f; pmB[c] = pmk[c] ? (&qev.x)[c] : 0.f; }
            }
            const float* A1 = (yy == 0) ? be : eb;
            const float* A2 = (yy == 0) ? bb : ee;
            const float* A3 = (yy == 0) ? cb : ce;
            const float* qT3 = (yy == 0) ? qbT : qeT;
            // slab1 (be/eb): no k-correction; eb additionally zero at j==I
#pragma unroll
            for (int jj = 0; jj < 16; ++jj) {
                const int j = 8 * jj + hw;
                const float4 v = *(const float4*)&A1[off4(b, I, j, K)];
                float d = pmA[0] * v.x + pmA[1] * v.y + pmA[2] * v.z + pmA[3] * v.w;
                if (yy == 1 && j == I) d = 0.f;
                acc[jj] = d;
            }
            // slab2 (bb/ee): subtract k==j
#pragma unroll
            for (int jj = 0; jj < 16; ++jj) {
                const int j = 8 * jj + hw;
                const float4 v = *(const float4*)&A2[off4(b, I, j, K)];
                float d = pmB[0] * v.x + pmB[1] * v.y + pmB[2] * v.z + pmB[3] * v.w;
#pragma unroll
                for (int c = 0; c < 4; ++c) d -= (K + c == j) ? pmB[c] * (&v.x)[c] : 0.f;
                acc[jj] += d;
            }
            // slab3 (cb/ce): per-j transposed coeff, skip k==j
#pragma unroll
            for (int jj = 0; jj < 16; ++jj) {
                const int j = 8 * jj + hw;
                const float4 v = *(const float4*)&A3[off4(b, I, j, K)];
                const float4 cf = *(const float4*)&qT3[off3(b, j, K)];
                float d = 0.f;
#pragma unroll
                for (int c = 0; c < 4; ++c) {
                    const float sc = pmk[c] ? (&cf.x)[c] : 0.f;
                    d += (K + c == j) ? 0.f : sc * (&v.x)[c];
                }
                acc[jj] += d;
            }
        }

#pragma unroll
        for (int jj = 0; jj < 16; ++jj) {
            const bool bit = (((jj < 8) ? Mlo : Mhi) >> (((jj & 7) << 3) + hw)) & 1;
            acc[jj] = bit ? acc[jj] : 0.f;
        }
#pragma unroll
        for (int o = 16; o > 0; o >>= 1) {
#pragma unroll
            for (int jj = 0; jj < 16; ++jj) acc[jj] += __shfl_xor(acc[jj], o);
        }
        // pack row I into LDS, then one coalesced float4 row store (NO atomics)
        if (lh < 16) rowbuf[8 * lh + hw] = acc[lh];
        __syncthreads();
        if (t < 32)
            *(float4*)&ws[(WP0 + yy) * BSS + off3(b, I, 4 * t)] = *(const float4*)&rowbuf[4 * t];
    } else {
        const float* A = (yy == 3) ? gb : ge;
        const float* qT = (yy == 3) ? qbT : qeT;
        const int Jt = x & 15, Is = x >> 4;
        const int J = 8 * Jt + hw, I0 = 16 * Is;

        const float4 q_J = (yy == 3) ? *(const float4*)&qs[off3(b, J, K)]
                                     : *(const float4*)&qsT[off3(b, J, K)];
        const int4 c0Kv = *(const int4*)&chart[off3(b, 0, K)];
        const bool c0J = chart[off3(b, 0, J)] != 0;
        const int Jprev = (J + S - 1) & (S - 1);
        const int4 chJKv = *(const int4*)&chart[off3(b, Jprev, K)];
        bool c0K[4], chJK[4], chKJ[4];
        int mxJ[4];
#pragma unroll
        for (int c = 0; c < 4; ++c) {
            c0K[c] = (&c0Kv.x)[c] != 0;
            chJK[c] = (&chJKv.x)[c] != 0;
            chKJ[c] = (yy == 4) ? (chart[off3(b, (K + c + S - 1) & (S - 1), J)] != 0) : false;
            mxJ[c] = J > (K + c) ? J : (K + c);
        }

        const unsigned long long MeIJ = __ballot(edge[off3(b, I0 + (l & 15), J)] != 0);
        const unsigned long long Mc0I = __ballot(chart[off3(b, 0, I0 + (l & 15))] != 0);
        const int hsh = l & 32;

        float accE[16];
        float rs[4] = {0.f, 0.f, 0.f, 0.f};

#pragma unroll
        for (int s = 0; s < 16; ++s) {
            const int I = I0 + s;
            const float4 v = *(const float4*)&A[off4(b, I, J, K)];
            const int4 eIKv = *(const int4*)&edge[off3(b, I, K)];
            const bool eIJ = (MeIJ >> (hsh + s)) & 1;
            const bool c0I = (Mc0I >> (hsh + s)) & 1;
            const float qT_JI = qT[off3(b, J, I)];

            float p_ = 0.f;
#pragma unroll
            for (int c = 0; c < 4; ++c) {
                const int Kc = K + c;
                const bool eIK = (&eIKv.x)[c] != 0;
                const float vv = (&v.x)[c];
                bool nc, o;
                if (yy == 3) {
                    nc = eIJ && eIK && (I != Kc) && (J <= Kc) && (J >= I || Kc <= I);
                    o = !((J <= I) && (Kc >= I)) && chJK[c] && (mxJ[c] != I) && c0K[c] && c0I;
                } else {
                    nc = eIK && eIJ && (I != J) && (Kc <= J) && (Kc >= I || J <= I);
                    o = !((Kc <= I) && (J >= I)) && chKJ[c] && (mxJ[c] != I) && c0J && c0I;
                }
                p_ += (nc ? (&q_J.x)[c] : 0.f) * vv;
                rs[c] += (o ? qT_JI : 0.f) * vv;
            }
            accE[s] = p_;
        }

#pragma unroll
        for (int o = 16; o > 0; o >>= 1) {
#pragma unroll
            for (int s = 0; s < 16; ++s) accE[s] += __shfl_xor(accE[s], o);
        }
        if (lh == 0) {
#pragma unroll
            for (int s = 0; s < 16; ++s)
                ws[((yy == 3) ? WAE0 : WAE1) * BSS + off3(b, I0 + s, J)] = accE[s];
        }
        // rs partials: single-writer per (Is) plane, plain stores
        if (yy == 3) {
            *(float4*)&ws[(WRS7 + Is) * BSS + off3(b, J, K)] =
                make_float4(rs[0], rs[1], rs[2], rs[3]);
        } else {
#pragma unroll
            for (int c = 0; c < 4; ++c)
                ws[(WRS8 + Is) * BSS + off3(b, K + c, J)] = rs[c];
        }
    }
}

extern "C" void kernel_launch(void* const* d_in, const int* in_sizes, int n_in,
                              void* d_out, int out_size, void* d_ws, size_t ws_size,
                              hipStream_t stream) {
    (void)in_sizes; (void)n_in; (void)out_size; (void)ws_size;
    const float* s_const = (const float*)d_in[0];
    const float* s_arg_begin = (const float*)d_in[1];
    const float* s_arg_end = (const float*)d_in[2];
    const float* be = (const float*)d_in[3];
    const float* eb = (const float*)d_in[4];
    const float* bb = (const float*)d_in[5];
    const float* ee = (const float*)d_in[6];
    const float* cb = (const float*)d_in[7];
    const float* ce = (const float*)d_in[8];
    const float* gb = (const float*)d_in[9];
    const float* ge = (const float*)d_in[10];
    const float* sp = (const float*)d_in[11];
    const int* edge = (const int*)d_in[12];
    const int* chart = (const int*)d_in[13];
    float* base = (float*)d_out;
    float* ws = (float*)d_ws;

    for (int it = 0; it < 3; ++it) {
        k_sigmoid<<<dim3(16, 3, BB), dim3(256), 0, stream>>>(s_arg_begin, s_arg_end, s_const,
                                                             base, ws, it == 0 ? 0 : 1);
        k_terms<<<dim3(S, 5, BB), dim3(256), 0, stream>>>(be, bb, cb, eb, ee, ce, sp, gb, ge,
                                                          edge, chart, ws);
    }
    k_sigmoid<<<dim3(16, 3, BB), dim3(256), 0, stream>>>(s_arg_begin, s_arg_end, s_const,
                                                         base, ws, 2);
}

// Round 3
// 465.016 us; speedup vs baseline: 1.2223x; 1.2223x over previous
//
#include <hip/hip_runtime.h>

#define BB 4
#define S 128
#define SS (S*S)
#define BSS (BB*SS)

__device__ __forceinline__ int off3(int b, int i, int j) { return (b * S + i) * S + j; }
__device__ __forceinline__ int off4(int b, int i, int j, int k) { return ((b * S + i) * S + j) * S + k; }

// ---------------------------------------------------------------------------
// sigmoid + LDS-tiled transpose (coalesced stores both ways).
// ws planes: qb[0], qe[1], qs[2], qbT[3], qeT[4], qsT[5], each BSS floats.
// ---------------------------------------------------------------------------
__global__ __launch_bounds__(256) void k_sigmoid(const float* __restrict__ sb,
                                                 const float* __restrict__ se,
                                                 const float* __restrict__ ss,
                                                 float* base,
                                                 float* __restrict__ ws, int init) {
    const int b = blockIdx.z, p = blockIdx.y;
    const int ti = blockIdx.x >> 2, tj = blockIdx.x & 3;
    const int col = threadIdx.x & 31, r0 = threadIdx.x >> 5;
    const float* src = (p == 0) ? sb : (p == 1) ? se : ss;

    __shared__ float tile[32][33];
#pragma unroll
    for (int rr = 0; rr < 4; ++rr) {
        const int row = r0 + 8 * rr;
        const int gi = 32 * ti + row, gj = 32 * tj + col;
        const float x = src[off3(b, gi, gj)];
        const float q = 1.0f / (1.0f + __expf(-x));
        ws[p * BSS + off3(b, gi, gj)] = q;
        if (init) base[p * BSS + off3(b, gi, gj)] = x;
        tile[row][col] = q;
    }
    __syncthreads();
#pragma unroll
    for (int rr = 0; rr < 4; ++rr) {
        const int rowo = r0 + 8 * rr;
        ws[(3 + p) * BSS + off3(b, 32 * tj + rowo, 32 * ti + col)] = tile[col][rowo];
    }
}

// ---------------------------------------------------------------------------
// Round-1 structure + explicit load batching for memory-level parallelism.
// grid = (128, 9, B). Each wave keeps 8-16 independent float4 loads in
// flight (batch-load to registers, then consume) instead of load->use->load.
// __launch_bounds__(256,3): VGPR cap ~170, 12 waves/CU.
// ---------------------------------------------------------------------------
__global__ __launch_bounds__(256, 3) void k_terms(
    const float* __restrict__ be, const float* __restrict__ bb,
    const float* __restrict__ cb, const float* __restrict__ eb,
    const float* __restrict__ ee, const float* __restrict__ ce,
    const float* __restrict__ sp, const float* __restrict__ gb,
    const float* __restrict__ ge, const int* __restrict__ edge,
    const int* __restrict__ chart, const float* __restrict__ ws,
    float* __restrict__ base) {
    const int b = blockIdx.z, y = blockIdx.y, x = blockIdx.x;
    const int t = threadIdx.x, hw = t >> 5, lh = t & 31, l = t & 63;
    const int K = 4 * lh;

    const float* qb = ws;
    const float* qe = ws + BSS;
    const float* qs = ws + 2 * BSS;
    const float* qbT = ws + 3 * BSS;
    const float* qeT = ws + 4 * BSS;
    const float* qsT = ws + 5 * BSS;

    if (y < 7) {
        const int I = x;
        const float* A;
        int plane;
        switch (y) {
            case 0: A = be; plane = 0; break;
            case 1: A = bb; plane = 0; break;
            case 2: A = cb; plane = 0; break;
            case 3: A = eb; plane = 1; break;
            case 4: A = ee; plane = 1; break;
            case 5: A = ce; plane = 1; break;
            default: A = sp; plane = 2; break;
        }
        const int Iprev = (I + S - 1) & (S - 1);

        // ballot-packed per-j bits (wave-uniform)
        const bool pe0 = edge[off3(b, I, l)] != 0;
        const bool pe1 = edge[off3(b, I, 64 + l)] != 0;
        unsigned long long Mlo = __ballot(pe0), Mhi = __ballot(pe1);
        if (y == 6) {
            const bool pc0 = chart[off3(b, 0, l)] != 0;
            const bool pc1 = chart[off3(b, 0, 64 + l)] != 0;
            const bool ph0 = chart[off3(b, Iprev, l)] != 0;
            const bool ph1 = chart[off3(b, Iprev, 64 + l)] != 0;
            Mlo = __ballot(pc0) & __ballot(ph0);
            Mhi = __ballot(pc1) & __ballot(ph1);
        } else if (y == 3) {  // fold (I != j) into the bit row
            if (I < 64) Mlo &= ~(1ull << I);
            else Mhi &= ~(1ull << (I - 64));
        }

        // per-lane pre-masked coefficients
        const float* qrow = (y == 0 || y == 4) ? qe : (y == 1 || y == 3) ? qb : qs;
        const float4 qv = *(const float4*)&qrow[off3(b, I, K)];
        const int4 ekv = *(const int4*)&edge[off3(b, I, K)];
        const int4 c0kv = *(const int4*)&chart[off3(b, 0, K)];
        float pm[4];
        bool pmask[4];
#pragma unroll
        for (int c = 0; c < 4; ++c) {
            const bool ek = (&ekv.x)[c] != 0;
            const bool c0k = (&c0kv.x)[c] != 0;
            const bool nI = (I != K + c);
            if (y == 0 || y == 1 || y == 4) pm[c] = (ek && nI) ? (&qv.x)[c] : 0.f;
            else if (y == 3) pm[c] = ek ? (&qv.x)[c] : 0.f;
            else if (y == 6) pm[c] = c0k ? (&qv.x)[c] : 0.f;
            pmask[c] = ek && nI;  // for y 2/5
        }
        const int corrSel = (y == 1 || y == 4) ? 1 : (y == 6) ? 2 : 0;
        const float* qT3 = (y == 2) ? qbT : qeT;

        float acc[16];
        if (y == 2 || y == 5) {
            // two 8-deep batches of (A, coeff) loads -> ~16 loads in flight
#pragma unroll
            for (int h = 0; h < 2; ++h) {
                float4 va[8], cf[8];
#pragma unroll
                for (int u = 0; u < 8; ++u) {
                    const int j = 8 * (8 * h + u) + hw;
                    va[u] = *(const float4*)&A[off4(b, I, j, K)];
                    cf[u] = *(const float4*)&qT3[off3(b, j, K)];
                }
#pragma unroll
                for (int u = 0; u < 8; ++u) {
                    const int jj = 8 * h + u;
                    const int j = 8 * jj + hw;
                    float dot = 0.f;
                    float s_[4];
#pragma unroll
                    for (int c = 0; c < 4; ++c) {
                        s_[c] = pmask[c] ? (&cf[u].x)[c] : 0.f;
                        dot += s_[c] * (&va[u].x)[c];
                    }
#pragma unroll
                    for (int c = 0; c < 4; ++c)
                        dot -= (K + c == j) ? s_[c] * (&va[u].x)[c] : 0.f;
                    const unsigned long long M = (jj < 8) ? Mlo : Mhi;
                    const bool bit = (M >> (((jj & 7) << 3) + hw)) & 1;
                    acc[jj] = bit ? dot : 0.f;
                }
            }
        } else {
            // all 16 A-row float4s prefetched to registers before compute
            float4 v[16];
#pragma unroll
            for (int jj = 0; jj < 16; ++jj)
                v[jj] = *(const float4*)&A[off4(b, I, 8 * jj + hw, K)];
#pragma unroll
            for (int jj = 0; jj < 16; ++jj) {
                const int j = 8 * jj + hw;
                float dot = pm[0] * v[jj].x + pm[1] * v[jj].y + pm[2] * v[jj].z + pm[3] * v[jj].w;
                const int ci = (corrSel == 0) ? 256 : (corrSel == 1) ? j : (I > j ? I : j);
#pragma unroll
                for (int c = 0; c < 4; ++c)
                    dot -= (K + c == ci) ? pm[c] * (&v[jj].x)[c] : 0.f;
                const unsigned long long M = (jj < 8) ? Mlo : Mhi;
                const bool bit = (M >> (((jj & 7) << 3) + hw)) & 1;
                acc[jj] = bit ? dot : 0.f;
            }
        }

#pragma unroll
        for (int o = 16; o > 0; o >>= 1) {
#pragma unroll
            for (int jj = 0; jj < 16; ++jj) acc[jj] += __shfl_xor(acc[jj], o);
        }
        if (lh == 0) {
#pragma unroll
            for (int jj = 0; jj < 16; ++jj)
                atomicAdd(&base[plane * BSS + off3(b, I, 8 * jj + hw)], acc[jj]);
        }
    } else {
        const float* A = (y == 7) ? gb : ge;
        const float* qT = (y == 7) ? qbT : qeT;
        const int Jt = x & 15, Is = x >> 4;
        const int J = 8 * Jt + hw, I0 = 16 * Is;

        const float4 q_J = (y == 7) ? *(const float4*)&qs[off3(b, J, K)]
                                    : *(const float4*)&qsT[off3(b, J, K)];
        const int4 c0Kv = *(const int4*)&chart[off3(b, 0, K)];
        const bool c0J = chart[off3(b, 0, J)] != 0;
        const int Jprev = (J + S - 1) & (S - 1);
        const int4 chJKv = *(const int4*)&chart[off3(b, Jprev, K)];
        bool c0K[4], chJK[4], chKJ[4];
        int mxJ[4];
#pragma unroll
        for (int c = 0; c < 4; ++c) {
            c0K[c] = (&c0Kv.x)[c] != 0;
            chJK[c] = (&chJKv.x)[c] != 0;
            chKJ[c] = (y == 8) ? (chart[off3(b, (K + c + S - 1) & (S - 1), J)] != 0) : false;
            mxJ[c] = J > (K + c) ? J : (K + c);
        }

        // ballots: eIJ bits and c0I bits for I = I0..I0+15 (this lane's J)
        const unsigned long long MeIJ = __ballot(edge[off3(b, I0 + (l & 15), J)] != 0);
        const unsigned long long Mc0I = __ballot(chart[off3(b, 0, I0 + (l & 15))] != 0);
        const int hsh = l & 32;

        // qT row J, cols I0..I0+15: 4 float4 loads instead of 16 scalars
        float4 qtv[4];
#pragma unroll
        for (int q4 = 0; q4 < 4; ++q4)
            qtv[q4] = *(const float4*)&qT[off3(b, J, I0 + 4 * q4)];

        float accE[16];
        float rs[4] = {0.f, 0.f, 0.f, 0.f};

        // two 8-deep batches of (A float4, edge int4) loads
#pragma unroll
        for (int hf = 0; hf < 2; ++hf) {
            float4 v[8];
            int4 ev[8];
#pragma unroll
            for (int u = 0; u < 8; ++u) {
                const int I = I0 + 8 * hf + u;
                v[u] = *(const float4*)&A[off4(b, I, J, K)];
                ev[u] = *(const int4*)&edge[off3(b, I, K)];
            }
#pragma unroll
            for (int u = 0; u < 8; ++u) {
                const int s = 8 * hf + u;
                const int I = I0 + s;
                const bool eIJ = (MeIJ >> (hsh + s)) & 1;
                const bool c0I = (Mc0I >> (hsh + s)) & 1;
                const float qT_JI = (&qtv[s >> 2].x)[s & 3];

                float p_ = 0.f;
#pragma unroll
                for (int c = 0; c < 4; ++c) {
                    const int Kc = K + c;
                    const bool eIK = (&ev[u].x)[c] != 0;
                    const float vv = (&v[u].x)[c];
                    bool nc, o;
                    if (y == 7) {
                        nc = eIJ && eIK && (I != Kc) && (J <= Kc) && (J >= I || Kc <= I);
                        o = !((J <= I) && (Kc >= I)) && chJK[c] && (mxJ[c] != I) && c0K[c] && c0I;
                    } else {
                        nc = eIK && eIJ && (I != J) && (Kc <= J) && (Kc >= I || J <= I);
                        o = !((Kc <= I) && (J >= I)) && chKJ[c] && (mxJ[c] != I) && c0J && c0I;
                    }
                    p_ += (nc ? (&q_J.x)[c] : 0.f) * vv;
                    rs[c] += (o ? qT_JI : 0.f) * vv;
                }
                accE[s] = p_;
            }
        }

#pragma unroll
        for (int o = 16; o > 0; o >>= 1) {
#pragma unroll
            for (int s = 0; s < 16; ++s) accE[s] += __shfl_xor(accE[s], o);
        }
        if (lh == 0) {
#pragma unroll
            for (int s = 0; s < 16; ++s)
                atomicAdd(&base[(y == 7 ? 0 : 1) * BSS + off3(b, I0 + s, J)], accE[s]);
        }

#pragma unroll
        for (int c = 0; c < 4; ++c) {
            if (y == 7)
                atomicAdd(&base[2 * BSS + off3(b, J, K + c)], rs[c]);
            else
                atomicAdd(&base[2 * BSS + off3(b, K + c, J)], rs[c]);
        }
    }
}

extern "C" void kernel_launch(void* const* d_in, const int* in_sizes, int n_in,
                              void* d_out, int out_size, void* d_ws, size_t ws_size,
                              hipStream_t stream) {
    (void)in_sizes; (void)n_in; (void)out_size; (void)ws_size;
    const float* s_const = (const float*)d_in[0];
    const float* s_arg_begin = (const float*)d_in[1];
    const float* s_arg_end = (const float*)d_in[2];
    const float* be = (const float*)d_in[3];
    const float* eb = (const float*)d_in[4];
    const float* bb = (const float*)d_in[5];
    const float* ee = (const float*)d_in[6];
    const float* cb = (const float*)d_in[7];
    const float* ce = (const float*)d_in[8];
    const float* gb = (const float*)d_in[9];
    const float* ge = (const float*)d_in[10];
    const float* sp = (const float*)d_in[11];
    const int* edge = (const int*)d_in[12];
    const int* chart = (const int*)d_in[13];
    float* base = (float*)d_out;
    float* ws = (float*)d_ws;

    for (int it = 0; it < 3; ++it) {
        if (it == 0)
            k_sigmoid<<<dim3(16, 3, BB), dim3(256), 0, stream>>>(s_arg_begin, s_arg_end,
                                                                 s_const, base, ws, 1);
        else
            k_sigmoid<<<dim3(16, 3, BB), dim3(256), 0, stream>>>(base, base + BSS,
                                                                 base + 2 * BSS, base, ws, 0);
        k_terms<<<dim3(S, 9, BB), dim3(256), 0, stream>>>(be, bb, cb, eb, ee, ce, sp, gb, ge,
                                                          edge, chart, ws, base);
    }
}